// Round 7
// baseline (278.259 us; speedup 1.0000x reference)
//
#include <hip/hip_runtime.h>

typedef __bf16 bf16;
typedef bf16 bf16x4 __attribute__((ext_vector_type(4)));
typedef bf16 bf16x8 __attribute__((ext_vector_type(8)));
typedef float floatx4 __attribute__((ext_vector_type(4)));
typedef unsigned int u32;
typedef unsigned long long u64;

#define B_ 8
#define S_ 2048
#define I_ 1024
#define H_ 64

// ---------------- Kernel A: fold scale + convert + pack W into B-frag lines ----
// Wf[(kc32*12 + nt)*512 + (g*16 + nl)*8 + j] = W[nt*16+nl][kc32*32 + g*8 + j]
// (rows 0-63 = Wq*0.125, 64-127 = Wk, 128-191 = Wv). Each (kc32,nt) line is the
// exact 1KB B-fragment a wave loads with one coalesced 16B/lane instruction.
__global__ void conv_w(const float* __restrict__ Wq, const float* __restrict__ bq,
                       const float* __restrict__ Wk, const float* __restrict__ bk,
                       const float* __restrict__ Wv, const float* __restrict__ bv,
                       bf16* __restrict__ Wf, float* __restrict__ bc) {
    int idx = blockIdx.x * 256 + threadIdx.x;   // 0 .. 192*1024-1
    int nrow = idx >> 10, i = idx & 1023;
    float v;
    if (nrow < 64)       v = Wq[nrow * I_ + i] * 0.125f;
    else if (nrow < 128) v = Wk[(nrow - 64) * I_ + i];
    else                 v = Wv[(nrow - 128) * I_ + i];
    int kc = i >> 5, t = i & 31, g = t >> 3, j = t & 7;
    int nt = nrow >> 4, nl = nrow & 15;
    Wf[(size_t)(kc * 12 + nt) * 512 + (g * 16 + nl) * 8 + j] = (bf16)v;
    if (idx < 192) {
        float bb = (idx < 64) ? bq[idx] * 0.125f
                 : (idx < 128) ? bk[idx - 64] : bv[idx - 128];
        bc[idx] = bb;
    }
}

// ---------------- Kernel B: QKV GEMM, wave-autonomous, barrier-free ----------------
// Grid 1024 x 64 threads (1 wave/block). Wave: M=16 rows x N=192, K=1024 in 8 slabs.
// W B-frags read directly from L2 (packed lines); X via wave-private LDS with
// register prefetch of the next slab. No __syncthreads anywhere.
__global__ __launch_bounds__(64) void qkv_gemm(const float* __restrict__ X,
                                               const bf16* __restrict__ Wf,
                                               const float* __restrict__ bc,
                                               bf16* __restrict__ Qd,
                                               bf16* __restrict__ Kd2,
                                               bf16* __restrict__ Vt2) {
    __shared__ __align__(16) bf16 Xs[16 * 136];

    int lane = threadIdx.x;
    int n = lane & 15, g = lane >> 4;
    int m0 = blockIdx.x * 16;

    floatx4 zero4 = {0.0f, 0.0f, 0.0f, 0.0f};
    floatx4 acc[12];
#pragma unroll
    for (int t = 0; t < 12; ++t) acc[t] = zero4;

    const float* xb = X + (size_t)m0 * I_;

    // preload slab 0 X into regs: inst q covers flat [q*256, q*256+255] of 16x128 tile
    float4 xr[8];
#pragma unroll
    for (int q = 0; q < 8; ++q) {
        int f = q * 256 + lane * 4;
        xr[q] = *(const float4*)(xb + (size_t)(f >> 7) * I_ + (f & 127));
    }

    for (int s = 0; s < 8; ++s) {
        // write this slab's X (regs -> LDS bf16)
#pragma unroll
        for (int q = 0; q < 8; ++q) {
            int f = q * 256 + lane * 4;
            bf16x4 xv;
            xv[0] = (bf16)xr[q].x; xv[1] = (bf16)xr[q].y;
            xv[2] = (bf16)xr[q].z; xv[3] = (bf16)xr[q].w;
            *(bf16x4*)(Xs + (f >> 7) * 136 + (f & 127)) = xv;
        }
        // prefetch next slab's X during compute
        if (s < 7) {
#pragma unroll
            for (int q = 0; q < 8; ++q) {
                int f = q * 256 + lane * 4;
                xr[q] = *(const float4*)(xb + (size_t)(f >> 7) * I_ + (s + 1) * 128 + (f & 127));
            }
        }
        // compute: 4 k-steps of 32; W frags straight from L2
#pragma unroll
        for (int ks = 0; ks < 4; ++ks) {
            bf16x8 xa = *(bf16x8*)(Xs + n * 136 + ks * 32 + g * 8);
            const bf16* wrow = Wf + (size_t)((s * 4 + ks) * 12) * 512 + lane * 8;
#pragma unroll
            for (int nt = 0; nt < 12; ++nt) {
                bf16x8 wb = *(const bf16x8*)(wrow + nt * 512);
                acc[nt] = __builtin_amdgcn_mfma_f32_16x16x32_bf16(xa, wb, acc[nt], 0, 0, 0);
            }
        }
    }

    // epilogue: C/D layout col=lane&15, row=g*4+r
    int b = m0 >> 11;
    int sb = (m0 & 2047) + g * 4;
#pragma unroll
    for (int nt = 0; nt < 12; ++nt) {
        int ng = nt * 16 + n;
        float bias = bc[ng];
        if (ng < 64) {
#pragma unroll
            for (int r = 0; r < 4; ++r)
                Qd[(size_t)(b * S_ + sb + r) * H_ + ng] = (bf16)(acc[nt][r] + bias);
        } else if (ng < 128) {
            int hc = (ng - 64) >> 3, j = (ng - 64) & 7;
#pragma unroll
            for (int r = 0; r < 4; ++r)
                Kd2[((size_t)(b * 8 + hc) * S_ + sb + r) * 8 + j] = (bf16)(acc[nt][r] + bias);
        } else {
            int hh = ng - 128, kc = sb >> 3, jj = sb & 7;
            bf16x4 pk;
#pragma unroll
            for (int r = 0; r < 4; ++r) pk[r] = (bf16)(acc[nt][r] + bias);
            *(bf16x4*)(Vt2 + ((size_t)(b * 256 + kc) * 64 + hh) * 8 + jj) = pk;
        }
    }
}

// ---------------- Kernel C: flash attention, barrier-free ----------------
// Grid 1024: bid=(b*32+qt)*4+ksp, block 256 (4 waves), q-tile 64, 512 k/block.
// K/V fragments loaded directly from global (coalesced 16B/lane); mask ballots
// held in registers (selected by g); P round-trips wave-private LDS rows.
// Zero __syncthreads.
__global__ __launch_bounds__(256, 2) void attn(const bf16* __restrict__ Qd,
                                               const bf16* __restrict__ Kd2,
                                               const bf16* __restrict__ Vt2,
                                               const int* __restrict__ mask,
                                               float* __restrict__ po,
                                               float* __restrict__ pl) {
    __shared__ __align__(16) bf16 Ps[64 * 136];   // 17 KB, rows w*16.. wave-private

    int tid = threadIdx.x;
    int w = tid >> 6, lane = tid & 63;
    int n = lane & 15, g = lane >> 4;
    int bid = blockIdx.x;
    int ksp = bid & 3;
    int qt = (bid >> 2) & 31;
    int b = bid >> 7;
    int q0 = qt * 64;

    const bf16* qptr = Qd + (size_t)(b * S_ + q0 + w * 16 + n) * H_ + g * 8;
    bf16x8 qa0 = *(const bf16x8*)qptr;
    bf16x8 qa1 = *(const bf16x8*)(qptr + 32);

    floatx4 zero4 = {0.0f, 0.0f, 0.0f, 0.0f};
    floatx4 o[4];
#pragma unroll
    for (int t = 0; t < 4; ++t) o[t] = zero4;
    float l_i[4] = {0.0f, 0.0f, 0.0f, 0.0f};

    const int* msl = mask + (size_t)(b * S_ + q0 + w * 16) * S_ + lane;
    const bf16* kp0 = Kd2 + (size_t)(b * 8 + g) * S_ * 8;
    const bf16* kp1 = Kd2 + (size_t)(b * 8 + 4 + g) * S_ * 8;
    const bf16* vp  = Vt2 + (size_t)(b * 256) * 512;   // *64*8

    for (int kt = ksp * 4; kt < ksp * 4 + 4; ++kt) {
        // ---- mask loads (consumed ~after QK; latency covered by program order) ----
        int mv[16][2];
#pragma unroll
        for (int rr = 0; rr < 16; ++rr)
#pragma unroll
            for (int c = 0; c < 2; ++c)
                mv[rr][c] = msl[(size_t)rr * S_ + kt * 128 + c * 64];

        // ---- S = Q K^T : K frags direct from global (16B/lane, n-contiguous) ----
        floatx4 s[8];
#pragma unroll
        for (int nt = 0; nt < 8; ++nt) {
            bf16x8 k0 = *(const bf16x8*)(kp0 + (size_t)(kt * 128 + nt * 16 + n) * 8);
            bf16x8 k1 = *(const bf16x8*)(kp1 + (size_t)(kt * 128 + nt * 16 + n) * 8);
            floatx4 a = zero4;
            a = __builtin_amdgcn_mfma_f32_16x16x32_bf16(qa0, k0, a, 0, 0, 0);
            a = __builtin_amdgcn_mfma_f32_16x16x32_bf16(qa1, k1, a, 0, 0, 0);
            s[nt] = a;
        }

        // ---- ballots: wave-uniform u64 per (row, 64-col chunk) ----
        u64 bal0[16], bal1[16];
#pragma unroll
        for (int rr = 0; rr < 16; ++rr) {
            bal0[rr] = __ballot(mv[rr][0] != 0);
            bal1[rr] = __ballot(mv[rr][1] != 0);
        }
        // select this lane's 4 q-rows (row = g*4+r) -> 4 u32 words of 128 bits
        u32 mq[4][4];
#pragma unroll
        for (int r = 0; r < 4; ++r) {
            u64 s0 = (g == 0) ? bal0[r] : (g == 1) ? bal0[4 + r]
                   : (g == 2) ? bal0[8 + r] : bal0[12 + r];
            u64 s1 = (g == 0) ? bal1[r] : (g == 1) ? bal1[4 + r]
                   : (g == 2) ? bal1[8 + r] : bal1[12 + r];
            mq[r][0] = (u32)s0; mq[r][1] = (u32)(s0 >> 32);
            mq[r][2] = (u32)s1; mq[r][3] = (u32)(s1 >> 32);
        }

        // ---- p = bit ? exp(s) : 0 (scores bounded; no max subtraction) ----
#pragma unroll
        for (int r = 0; r < 4; ++r)
#pragma unroll
            for (int nt = 0; nt < 8; ++nt) {
                float e = __expf(s[nt][r]);
                bool bit = (mq[r][nt >> 1] >> ((nt & 1) * 16 + n)) & 1u;
                float p = bit ? e : 0.0f;
                s[nt][r] = p;
                l_i[r] += p;
            }

        // ---- P: C-layout -> wave-private LDS rows -> A-layout ----
#pragma unroll
        for (int r = 0; r < 4; ++r)
#pragma unroll
            for (int nt = 0; nt < 8; ++nt)
                Ps[(w * 16 + g * 4 + r) * 136 + nt * 16 + n] = (bf16)s[nt][r];

        // ---- O += P V : V frags direct from global ----
#pragma unroll
        for (int k0 = 0; k0 < 4; ++k0) {
            bf16x8 pa = *(bf16x8*)(Ps + (w * 16 + n) * 136 + k0 * 32 + g * 8);
#pragma unroll
            for (int ht = 0; ht < 4; ++ht) {
                bf16x8 vb = *(const bf16x8*)(vp +
                    ((size_t)(kt * 16 + k0 * 4 + g) * 64 + ht * 16 + n) * 8);
                o[ht] = __builtin_amdgcn_mfma_f32_16x16x32_bf16(pa, vb, o[ht], 0, 0, 0);
            }
        }
    }

    // ---- final row-sum reduce (once) ----
#pragma unroll
    for (int r = 0; r < 4; ++r)
#pragma unroll
        for (int off = 1; off < 16; off <<= 1)
            l_i[r] += __shfl_xor(l_i[r], off, 64);

    float* pb = po + (size_t)bid * 4096;
#pragma unroll
    for (int ht = 0; ht < 4; ++ht)
#pragma unroll
        for (int r = 0; r < 4; ++r)
            pb[(w * 16 + g * 4 + r) * 64 + ht * 16 + n] = o[ht][r];
    if (n == 0) {
#pragma unroll
        for (int r = 0; r < 4; ++r)
            pl[(size_t)bid * 64 + w * 16 + g * 4 + r] = l_i[r];
    }
}

// ---------------- Kernel D: merge 4 k-split partials (plain sums) ----------------
__global__ __launch_bounds__(256) void reduce_o(const float* __restrict__ po,
                                                const float* __restrict__ pl,
                                                float* __restrict__ out) {
    int idx = blockIdx.x * 256 + threadIdx.x;   // (q,h): 16384*64
    int h = idx & 63, q = idx >> 6;
    int b = q >> 11, qq = q & 2047;
    int qt = qq >> 6, ql = qq & 63;
    int bid0 = (b * 32 + qt) * 4;
    float num = 0.0f, den = 0.0f;
#pragma unroll
    for (int j = 0; j < 4; ++j) {
        den += pl[(size_t)(bid0 + j) * 64 + ql];
        num += po[(size_t)(bid0 + j) * 4096 + ql * 64 + h];
    }
    out[(size_t)q * 64 + h] = num / den;
}

extern "C" void kernel_launch(void* const* d_in, const int* in_sizes, int n_in,
                              void* d_out, int out_size, void* d_ws, size_t ws_size,
                              hipStream_t stream) {
    const float* X    = (const float*)d_in[0];
    const int*   mask = (const int*)d_in[1];
    const float* Wq   = (const float*)d_in[2];
    const float* bq   = (const float*)d_in[3];
    const float* Wk   = (const float*)d_in[4];
    const float* bk   = (const float*)d_in[5];
    const float* Wv   = (const float*)d_in[6];
    const float* bv   = (const float*)d_in[7];
    float* out = (float*)d_out;

    char* p = (char*)d_ws;
    bf16* Qd   = (bf16*)p;  p += (size_t)B_ * S_ * H_ * 2;      // 2 MB
    bf16* Kd2  = (bf16*)p;  p += (size_t)B_ * S_ * H_ * 2;      // 2 MB
    bf16* Vt2  = (bf16*)p;  p += (size_t)B_ * S_ * H_ * 2;      // 2 MB
    bf16* Wf   = (bf16*)p;  p += (size_t)192 * 1024 * 2;        // 384 KB packed W
    float* bc  = (float*)p; p += 1024;
    float* po  = (float*)p; p += (size_t)1024 * 4096 * 4;       // 16 MB
    float* pl  = (float*)p; p += (size_t)1024 * 64 * 4;         // 256 KB

    conv_w<<<dim3(768), dim3(256), 0, stream>>>(Wq, bq, Wk, bk, Wv, bv, Wf, bc);
    qkv_gemm<<<dim3(1024), dim3(64), 0, stream>>>(X, Wf, bc, Qd, Kd2, Vt2);
    attn<<<dim3(1024), dim3(256), 0, stream>>>(Qd, Kd2, Vt2, mask, po, pl);
    reduce_o<<<dim3(4096), dim3(256), 0, stream>>>(po, pl, out);
}